// Round 1
// baseline (179.078 us; speedup 1.0000x reference)
//
#include <hip/hip_runtime.h>
#include <math.h>

#define NTOK 197
#define BATCH 8
#define DIMV 64
#define MSPLIT 13
#define QKSCALE 0.17677669529663687f  /* 32^-0.5 */

// ---------------------------------------------------------------------------
// Kernel 1: LayerNorm + QK projection.
// grid = B*N blocks, 64 threads (one wave) per (b,n) row.
// Writes xn in [m][b][d] layout (so kernel 3 can stage xn[:,m,:] contiguously),
// q,k in [bh][n][d32] layout (bh = h*8+b) for kernel 2.
// ---------------------------------------------------------------------------
__global__ __launch_bounds__(64) void k1_ln_qk(
    const float* __restrict__ x, const float* __restrict__ gamma,
    const float* __restrict__ beta, const float* __restrict__ wqk,
    float* __restrict__ xn, float* __restrict__ q, float* __restrict__ k) {
  int bid = blockIdx.x;            // b*NTOK + n
  int b = bid / NTOK, n = bid % NTOK;
  int d = threadIdx.x;             // 0..63
  float v = x[(size_t)(b * NTOK + n) * DIMV + d];
  float s = v, s2 = v * v;
  #pragma unroll
  for (int off = 32; off; off >>= 1) {
    s  += __shfl_xor(s, off);
    s2 += __shfl_xor(s2, off);
  }
  float mu  = s * (1.0f / 64.0f);
  float var = s2 * (1.0f / 64.0f) - mu * mu;
  float r   = rsqrtf(var + 1e-5f);
  float xv  = (v - mu) * r * gamma[d] + beta[d];
  xn[(size_t)(n * BATCH + b) * DIMV + d] = xv;

  __shared__ float xs[DIMV];
  xs[d] = xv;
  __syncthreads();

  float a0 = 0.f, a1 = 0.f;
  #pragma unroll 8
  for (int dd = 0; dd < DIMV; ++dd) {
    float xr = xs[dd];
    a0 = fmaf(xr, wqk[dd * 128 + d], a0);        // q column d
    a1 = fmaf(xr, wqk[dd * 128 + 64 + d], a1);   // k column d
  }
  int h = d >> 5, d32 = d & 31;
  int bh = h * BATCH + b;
  q[((size_t)bh * NTOK + n) * 32 + d32] = a0 * QKSCALE;  // fold scale into q
  k[((size_t)bh * NTOK + n) * 32 + d32] = a1;
}

// ---------------------------------------------------------------------------
// Kernel 2: dots + softmax. grid = 16*N blocks (one per (bh,n) row), 256 thr.
// attn written as [n][bh][m] (rows contiguous in m -> coalesced).
// ---------------------------------------------------------------------------
__global__ __launch_bounds__(256) void k2_attn(
    const float* __restrict__ q, const float* __restrict__ k,
    float* __restrict__ attn) {
  int id = blockIdx.x;             // bh*NTOK + n
  int bh = id / NTOK, n = id % NTOK;
  int t = threadIdx.x;

  __shared__ float qs[32];
  __shared__ float redmx[4];
  __shared__ float redsm[4];
  if (t < 32) qs[t] = q[((size_t)bh * NTOK + n) * 32 + t];
  __syncthreads();

  int m = t;
  float sdot = -3.0e38f;
  if (m < NTOK) {
    const float4* kr = (const float4*)&k[((size_t)bh * NTOK + m) * 32];
    const float4* qr = (const float4*)qs;
    float acc = 0.f;
    #pragma unroll
    for (int i = 0; i < 8; ++i) {
      float4 kv = kr[i], qv = qr[i];
      acc = fmaf(kv.x, qv.x, acc);
      acc = fmaf(kv.y, qv.y, acc);
      acc = fmaf(kv.z, qv.z, acc);
      acc = fmaf(kv.w, qv.w, acc);
    }
    sdot = acc;                    // scale already folded into q
  }
  // block max
  float mx = sdot;
  #pragma unroll
  for (int off = 32; off; off >>= 1) mx = fmaxf(mx, __shfl_xor(mx, off));
  int wid = t >> 6;
  if ((t & 63) == 0) redmx[wid] = mx;
  __syncthreads();
  mx = fmaxf(fmaxf(redmx[0], redmx[1]), fmaxf(redmx[2], redmx[3]));

  float p = (m < NTOK) ? __expf(sdot - mx) : 0.f;
  float sm = p;
  #pragma unroll
  for (int off = 32; off; off >>= 1) sm += __shfl_xor(sm, off);
  if ((t & 63) == 0) redsm[wid] = sm;
  __syncthreads();
  sm = (redsm[0] + redsm[1]) + (redsm[2] + redsm[3]);

  if (m < NTOK) attn[((size_t)n * 16 + bh) * NTOK + m] = p / sm;
}

// ---------------------------------------------------------------------------
// Kernel 3: the big einsum.
//   out_part[s][n][b][e] = sum_{m in split s} attn[b,h(e),n,m] * (xn[b,m,:]@W_u(n,m))[e]
// block = (s,n); 256 threads: t = eg*8+dp, eg in [0,32) handles e0=eg (head 0)
// and e1=eg+32 (head 1); dp in [0,8) handles d-chunk dp*8..dp*8+7.
// W staged in LDS [d][65] (pad 65 -> 2-way max on column reads = free),
// xn staged [b][72] (b128-aligned, broadcast), both double-buffered.
// ---------------------------------------------------------------------------
__global__ __launch_bounds__(256) void k3_main(
    const float* __restrict__ xn, const float* __restrict__ attn,
    const float* __restrict__ up, const int* __restrict__ imap,
    float* __restrict__ part) {
  int bid = blockIdx.x;            // s*NTOK + n
  int s = bid / NTOK, n = bid % NTOK;
  int m0 = (NTOK * s) / MSPLIT, m1 = (NTOK * (s + 1)) / MSPLIT;
  int mlen = m1 - m0;
  int t = threadIdx.x;
  int eg = t >> 3, dp = t & 7;

  __shared__ float Ws[2][64 * 65];
  __shared__ float xs[2][8 * 72];
  __shared__ float as[16 * 16];    // [mi][bh], mi < 16

  // stage attn chunk for this block (one-time)
  for (int i = t; i < mlen * 16; i += 256) {
    int bh = i / mlen, mi = i - bh * mlen;
    as[mi * 16 + bh] = attn[((size_t)n * 16 + bh) * NTOK + (m0 + mi)];
  }
  // stage first W and xn into buffer 0
  {
    int u = imap[n * NTOK + m0];
    const float4* wg = (const float4*)(up + (size_t)u * 4096);
    #pragma unroll
    for (int kk = 0; kk < 4; ++kk) {
      int idx = t + kk * 256;
      float4 v = wg[idx];
      int d = idx >> 4, e4 = (idx & 15) * 4;
      float* dst = &Ws[0][d * 65 + e4];
      dst[0] = v.x; dst[1] = v.y; dst[2] = v.z; dst[3] = v.w;
    }
    if (t < 128) {
      float4 v = ((const float4*)&xn[(size_t)m0 * 512])[t];
      int b = t >> 4, d4 = t & 15;
      *(float4*)&xs[0][b * 72 + d4 * 4] = v;
    }
  }
  __syncthreads();

  float accA[8], accB[8];
  #pragma unroll
  for (int b = 0; b < 8; ++b) { accA[b] = 0.f; accB[b] = 0.f; }

  int buf = 0;
  for (int m = m0; m < m1; ++m) {
    // ---- prefetch next tile into registers (hides global latency) ----
    float4 wreg[4];
    float4 xreg;
    bool havenext = (m + 1 < m1);
    if (havenext) {
      int u = imap[n * NTOK + m + 1];
      const float4* wg = (const float4*)(up + (size_t)u * 4096);
      #pragma unroll
      for (int kk = 0; kk < 4; ++kk) wreg[kk] = wg[t + kk * 256];
      if (t < 128) xreg = ((const float4*)&xn[(size_t)(m + 1) * 512])[t];
    }

    // ---- compute on current buffer ----
    int mi = m - m0;
    float av0[8], av1[8];
    #pragma unroll
    for (int b = 0; b < 8; ++b) {
      av0[b] = as[mi * 16 + b];          // head 0, batch b (broadcast)
      av1[b] = as[mi * 16 + 8 + b];      // head 1, batch b
    }
    float w0[8], w1[8];
    const float* wsrc = &Ws[buf][dp * 8 * 65];
    #pragma unroll
    for (int i = 0; i < 8; ++i) {
      w0[i] = wsrc[i * 65 + eg];
      w1[i] = wsrc[i * 65 + eg + 32];
    }
    #pragma unroll
    for (int b = 0; b < 8; ++b) {
      const float* xrow = &xs[buf][b * 72 + dp * 8];
      float4 xa = *(const float4*)xrow;
      float4 xb = *(const float4*)(xrow + 4);
      float p0, p1;
      p0 = w0[0] * xa.x; p1 = w1[0] * xa.x;
      p0 = fmaf(w0[1], xa.y, p0); p1 = fmaf(w1[1], xa.y, p1);
      p0 = fmaf(w0[2], xa.z, p0); p1 = fmaf(w1[2], xa.z, p1);
      p0 = fmaf(w0[3], xa.w, p0); p1 = fmaf(w1[3], xa.w, p1);
      p0 = fmaf(w0[4], xb.x, p0); p1 = fmaf(w1[4], xb.x, p1);
      p0 = fmaf(w0[5], xb.y, p0); p1 = fmaf(w1[5], xb.y, p1);
      p0 = fmaf(w0[6], xb.z, p0); p1 = fmaf(w1[6], xb.z, p1);
      p0 = fmaf(w0[7], xb.w, p0); p1 = fmaf(w1[7], xb.w, p1);
      accA[b] = fmaf(av0[b], p0, accA[b]);
      accB[b] = fmaf(av1[b], p1, accB[b]);
    }

    // ---- write prefetched tile into other buffer ----
    if (havenext) {
      #pragma unroll
      for (int kk = 0; kk < 4; ++kk) {
        int idx = t + kk * 256;
        int d = idx >> 4, e4 = (idx & 15) * 4;
        float* dst = &Ws[buf ^ 1][d * 65 + e4];
        dst[0] = wreg[kk].x; dst[1] = wreg[kk].y;
        dst[2] = wreg[kk].z; dst[3] = wreg[kk].w;
      }
      if (t < 128) {
        int b = t >> 4, d4 = t & 15;
        *(float4*)&xs[buf ^ 1][b * 72 + d4 * 4] = xreg;
      }
    }
    __syncthreads();
    buf ^= 1;
  }

  // reduce partial dots across the 8 dp lanes (lanes differing in bits 0..2)
  #pragma unroll
  for (int off = 1; off <= 4; off <<= 1) {
    #pragma unroll
    for (int b = 0; b < 8; ++b) {
      accA[b] += __shfl_xor(accA[b], off);
      accB[b] += __shfl_xor(accB[b], off);
    }
  }
  if (dp == 0) {
    float* po = &part[(((size_t)s * NTOK + n) * BATCH) * 64];
    #pragma unroll
    for (int b = 0; b < 8; ++b) {
      po[b * 64 + eg]      = accA[b];
      po[b * 64 + eg + 32] = accB[b];
    }
  }
}

// ---------------------------------------------------------------------------
// Kernel 4: combine splits + output projection + bias.
// block per n, 512 threads: t = b*64 + e (phase 1) / b*64 + d (phase 2).
// ---------------------------------------------------------------------------
__global__ __launch_bounds__(512) void k4_out(
    const float* __restrict__ part, const float* __restrict__ wout,
    const float* __restrict__ bout, float* __restrict__ out) {
  int n = blockIdx.x;
  int t = threadIdx.x;
  int b = t >> 6, e = t & 63;

  __shared__ float is[BATCH * 64];
  float acc = 0.f;
  #pragma unroll
  for (int s = 0; s < MSPLIT; ++s)
    acc += part[(((size_t)s * NTOK + n) * BATCH + b) * 64 + e];
  is[b * 64 + e] = acc;
  __syncthreads();

  int d = e;
  float o = bout[d];
  const float* ir = &is[b * 64];
  #pragma unroll 8
  for (int ee = 0; ee < 64; ++ee)
    o = fmaf(ir[ee], wout[ee * 64 + d], o);
  out[((size_t)b * NTOK + n) * DIMV + d] = o;
}

// ---------------------------------------------------------------------------
extern "C" void kernel_launch(void* const* d_in, const int* in_sizes, int n_in,
                              void* d_out, int out_size, void* d_ws, size_t ws_size,
                              hipStream_t stream) {
  const float* x     = (const float*)d_in[0];
  const float* gamma = (const float*)d_in[1];
  const float* beta  = (const float*)d_in[2];
  const float* wqk   = (const float*)d_in[3];
  const float* up    = (const float*)d_in[4];
  const float* wout  = (const float*)d_in[5];
  const float* bout  = (const float*)d_in[6];
  const int*   imap  = (const int*)d_in[7];
  float* out = (float*)d_out;

  float* ws   = (float*)d_ws;
  float* xn   = ws;                       // [197][8][64]   = 100864 floats
  float* q    = xn + 100864;              // [16][197][32]  = 100864
  float* k    = q + 100864;               // [16][197][32]  = 100864
  float* attn = k + 100864;               // [197][16][197] = 620944
  float* part = attn + 620944;            // [13][197][8][64] = 1311232
                                          // total ~9.0 MB of ws

  k1_ln_qk<<<BATCH * NTOK, 64, 0, stream>>>(x, gamma, beta, wqk, xn, q, k);
  k2_attn<<<16 * NTOK, 256, 0, stream>>>(q, k, attn);
  k3_main<<<MSPLIT * NTOK, 256, 0, stream>>>(xn, attn, up, imap, part);
  k4_out<<<NTOK, 512, 0, stream>>>(part, wout, bout, out);
}

// Round 2
// 166.410 us; speedup vs baseline: 1.0761x; 1.0761x over previous
//
#include <hip/hip_runtime.h>
#include <math.h>

#define NTOK 197
#define BATCH 8
#define SPL 4
#define QKSCALE 0.17677669529663687f  /* 32^-0.5 */

typedef float f32x4 __attribute__((ext_vector_type(4)));
typedef short bf16x8 __attribute__((ext_vector_type(8)));

union U4S8 { uint4 u4; unsigned u[4]; bf16x8 s; };

// pack two f32 -> packed bf16x2 (RNE) via HW cvt_pk
__device__ inline unsigned pack2(float lo, float hi) {
  unsigned r;
  asm("v_cvt_pk_bf16_f32 %0, %1, %2" : "=v"(r) : "v"(lo), "v"(hi));
  return r;
}

// unpack 2 bf16 from u32, multiply by s, repack
__device__ inline unsigned mulpack(unsigned v, float s) {
  float lo = __uint_as_float(v << 16) * s;
  float hi = __uint_as_float(v & 0xffff0000u) * s;
  return pack2(lo, hi);
}

// ---------------------------------------------------------------------------
// Kernel 0: transpose + convert unique_params [u][d][e] f32 -> wt [u][e][d] bf16
// block per u, 256 threads: t -> (e = t>>2, dg = t&3); thread writes
// wt[u][e][dg*16 .. +16) (32 B contiguous, wave-coalesced).
// ---------------------------------------------------------------------------
__global__ __launch_bounds__(256) void k0_wt(const float* __restrict__ up,
                                             unsigned short* __restrict__ wt) {
  int u = blockIdx.x;
  int t = threadIdx.x;
  int e = t >> 2, dg = t & 3;
  const float* src = up + (size_t)u * 4096 + dg * 16 * 64 + e;
  unsigned out[8];
  #pragma unroll
  for (int j = 0; j < 8; ++j) {
    float f0 = src[(2 * j) * 64];
    float f1 = src[(2 * j + 1) * 64];
    out[j] = pack2(f0, f1);
  }
  unsigned short* dst = wt + (size_t)u * 4096 + e * 64 + dg * 16;
  *(uint4*)dst = make_uint4(out[0], out[1], out[2], out[3]);
  *(uint4*)(dst + 8) = make_uint4(out[4], out[5], out[6], out[7]);
}

// ---------------------------------------------------------------------------
// Kernel 1: LayerNorm + QK projection. grid = B*N blocks, 64 threads.
// Writes xnb (bf16) in [m][b][d] layout, q,k f32 in [bh][n][d32].
// ---------------------------------------------------------------------------
__global__ __launch_bounds__(64) void k1_ln_qk(
    const float* __restrict__ x, const float* __restrict__ gamma,
    const float* __restrict__ beta, const float* __restrict__ wqk,
    unsigned short* __restrict__ xnb, float* __restrict__ q,
    float* __restrict__ k) {
  int bid = blockIdx.x;            // b*NTOK + n
  int b = bid / NTOK, n = bid % NTOK;
  int d = threadIdx.x;             // 0..63
  float v = x[(size_t)(b * NTOK + n) * 64 + d];
  float s = v, s2 = v * v;
  #pragma unroll
  for (int off = 32; off; off >>= 1) {
    s  += __shfl_xor(s, off);
    s2 += __shfl_xor(s2, off);
  }
  float mu  = s * (1.0f / 64.0f);
  float var = s2 * (1.0f / 64.0f) - mu * mu;
  float rr  = rsqrtf(var + 1e-5f);
  float xv  = (v - mu) * rr * gamma[d] + beta[d];

  // bf16 (RNE) store into [m][b][d]
  unsigned ub = __float_as_uint(xv);
  ub += 0x7fff + ((ub >> 16) & 1);
  xnb[(size_t)(n * BATCH + b) * 64 + d] = (unsigned short)(ub >> 16);

  __shared__ float xs[64];
  xs[d] = xv;
  __syncthreads();

  float a0 = 0.f, a1 = 0.f;
  #pragma unroll 8
  for (int dd = 0; dd < 64; ++dd) {
    float xr = xs[dd];
    a0 = fmaf(xr, wqk[dd * 128 + d], a0);
    a1 = fmaf(xr, wqk[dd * 128 + 64 + d], a1);
  }
  int h = d >> 5, d32 = d & 31;
  int bh = h * BATCH + b;
  q[((size_t)bh * NTOK + n) * 32 + d32] = a0 * QKSCALE;
  k[((size_t)bh * NTOK + n) * 32 + d32] = a1;
}

// ---------------------------------------------------------------------------
// Kernel 2: dots + softmax. grid = 16*N blocks, 256 thr.
// attn written as [n][m][bh] (16 f32 per (n,m), for k3's broadcast reads).
// ---------------------------------------------------------------------------
__global__ __launch_bounds__(256) void k2_attn(
    const float* __restrict__ q, const float* __restrict__ k,
    float* __restrict__ attn) {
  int id = blockIdx.x;             // bh*NTOK + n
  int bh = id / NTOK, n = id % NTOK;
  int t = threadIdx.x;

  __shared__ float qs[32];
  __shared__ float redmx[4];
  __shared__ float redsm[4];
  if (t < 32) qs[t] = q[((size_t)bh * NTOK + n) * 32 + t];
  __syncthreads();

  int m = t;
  float sdot = -3.0e38f;
  if (m < NTOK) {
    const float4* kr = (const float4*)&k[((size_t)bh * NTOK + m) * 32];
    const float4* qr = (const float4*)qs;
    float acc = 0.f;
    #pragma unroll
    for (int i = 0; i < 8; ++i) {
      float4 kv = kr[i], qv = qr[i];
      acc = fmaf(kv.x, qv.x, acc);
      acc = fmaf(kv.y, qv.y, acc);
      acc = fmaf(kv.z, qv.z, acc);
      acc = fmaf(kv.w, qv.w, acc);
    }
    sdot = acc;
  }
  float mx = sdot;
  #pragma unroll
  for (int off = 32; off; off >>= 1) mx = fmaxf(mx, __shfl_xor(mx, off));
  int wid = t >> 6;
  if ((t & 63) == 0) redmx[wid] = mx;
  __syncthreads();
  mx = fmaxf(fmaxf(redmx[0], redmx[1]), fmaxf(redmx[2], redmx[3]));

  float p = (m < NTOK) ? __expf(sdot - mx) : 0.f;
  float sm = p;
  #pragma unroll
  for (int off = 32; off; off >>= 1) sm += __shfl_xor(sm, off);
  if ((t & 63) == 0) redsm[wid] = sm;
  __syncthreads();
  sm = (redsm[0] + redsm[1]) + (redsm[2] + redsm[3]);

  if (m < NTOK) attn[((size_t)n * NTOK + m) * 16 + bh] = p / sm;
}

// ---------------------------------------------------------------------------
// Kernel 3: main einsum via MFMA.
// Per n: out[(b,h), e] = sum_{(m,d)} (attn[b,h,n,m]*xn_bf16[b,m,d]) * Wt[u(n,m)][e][d]
// grid = 197*4 blocks (XCD-swizzled), 256 thr = 4 waves; each wave owns a
// (n, m-subrange) and computes the full 16x64 tile (4 e-tiles, 16 f32 acc).
// A-frags built in registers (no LDS, no __syncthreads). B-frags are direct
// 16-B global loads from the transposed bf16 W.
// ---------------------------------------------------------------------------
__global__ __launch_bounds__(256) void k3_main(
    const unsigned short* __restrict__ xnb, const float* __restrict__ attn,
    const unsigned short* __restrict__ wt, const int* __restrict__ imap,
    float* __restrict__ part) {
  int bid = blockIdx.x;
  // bijective XCD swizzle over 788 blocks (q=98, r=4): contiguous swz per XCD
  int xcd = bid & 7, idx = bid >> 3;
  int swz = (xcd < 4) ? xcd * 99 + idx : 396 + (xcd - 4) * 98 + idx;
  int n = swz >> 2, s = swz & 3;
  int w = threadIdx.x >> 6, lane = threadIdx.x & 63;
  int mA = (NTOK * s) / SPL, mB = (NTOK * (s + 1)) / SPL;
  int len = mB - mA;
  int m0 = mA + (len * w) / 4, m1 = mA + (len * (w + 1)) / 4;

  int r = lane & 15;               // A row = h*8+b ; also B col index
  int g = lane >> 4;               // k-subgroup
  int b = r & 7;

  f32x4 acc[4];
  #pragma unroll
  for (int t = 0; t < 4; ++t) acc[t] = (f32x4)0.0f;

  const unsigned short* xbase = xnb + b * 64 + 8 * g;

  // prologue: loads for m0
  int u = imap[n * NTOK + m0];
  uint4 xv0 = *(const uint4*)(xbase + (size_t)m0 * 512);
  uint4 xv1 = *(const uint4*)(xbase + (size_t)m0 * 512 + 32);
  float av  = attn[((size_t)n * NTOK + m0) * 16 + r];

  for (int m = m0; m < m1; ++m) {
    // B loads for current m (u loaded one iter ahead)
    U4S8 bf[4][2];
    const unsigned short* wp = wt + (size_t)u * 4096 + r * 64 + 8 * g;
    #pragma unroll
    for (int t = 0; t < 4; ++t) {
      bf[t][0].s = *(const bf16x8*)(wp + t * 16 * 64);
      bf[t][1].s = *(const bf16x8*)(wp + t * 16 * 64 + 32);
    }
    // prefetch next m's A inputs + u (clamped to stay in-bounds)
    int mn = (m + 1 < m1) ? m + 1 : m;
    int un = imap[n * NTOK + mn];
    uint4 nx0 = *(const uint4*)(xbase + (size_t)mn * 512);
    uint4 nx1 = *(const uint4*)(xbase + (size_t)mn * 512 + 32);
    float an  = attn[((size_t)n * NTOK + mn) * 16 + r];

    // build A-frags in registers: bf16(attn * xn)
    U4S8 a0, a1;
    #pragma unroll
    for (int qd = 0; qd < 4; ++qd) {
      a0.u[qd] = mulpack(((const unsigned*)&xv0)[qd], av);
      a1.u[qd] = mulpack(((const unsigned*)&xv1)[qd], av);
    }
    // 8 MFMAs: 4 e-tiles x 2 K-steps
    #pragma unroll
    for (int t = 0; t < 4; ++t) {
      acc[t] = __builtin_amdgcn_mfma_f32_16x16x32_bf16(a0.s, bf[t][0].s, acc[t], 0, 0, 0);
      acc[t] = __builtin_amdgcn_mfma_f32_16x16x32_bf16(a1.s, bf[t][1].s, acc[t], 0, 0, 0);
    }
    xv0 = nx0; xv1 = nx1; av = an; u = un;
  }

  // epilogue: D rows = 4g+reg -> (h=g>>1, b=4(g&1)+reg); keep e-tiles of own head
  int slot = s * 4 + w;
  int c = lane & 15;
  int hb = 4 * (g & 1);
  float* po = part + (((size_t)slot * NTOK + n) * BATCH) * 64;
  #pragma unroll
  for (int t = 0; t < 4; ++t) {
    if ((g >> 1) == (t >> 1)) {
      #pragma unroll
      for (int reg = 0; reg < 4; ++reg) {
        po[(hb + reg) * 64 + 16 * t + c] = acc[t][reg];
      }
    }
  }
}

// ---------------------------------------------------------------------------
// Kernel 4: combine 16 partial slots + output projection + bias.
// block per n, 512 threads.
// ---------------------------------------------------------------------------
__global__ __launch_bounds__(512) void k4_out(
    const float* __restrict__ part, const float* __restrict__ wout,
    const float* __restrict__ bout, float* __restrict__ out) {
  int n = blockIdx.x;
  int t = threadIdx.x;
  int b = t >> 6, e = t & 63;

  __shared__ float is[BATCH * 64];
  float acc = 0.f;
  #pragma unroll
  for (int p = 0; p < 16; ++p)
    acc += part[(((size_t)p * NTOK + n) * BATCH + b) * 64 + e];
  is[b * 64 + e] = acc;
  __syncthreads();

  float o = bout[e];
  const float* ir = &is[b * 64];
  #pragma unroll 8
  for (int ee = 0; ee < 64; ++ee)
    o = fmaf(ir[ee], wout[ee * 64 + e], o);
  out[((size_t)b * NTOK + n) * 64 + e] = o;
}

// ---------------------------------------------------------------------------
extern "C" void kernel_launch(void* const* d_in, const int* in_sizes, int n_in,
                              void* d_out, int out_size, void* d_ws, size_t ws_size,
                              hipStream_t stream) {
  const float* x     = (const float*)d_in[0];
  const float* gamma = (const float*)d_in[1];
  const float* beta  = (const float*)d_in[2];
  const float* wqk   = (const float*)d_in[3];
  const float* up    = (const float*)d_in[4];
  const float* wout  = (const float*)d_in[5];
  const float* bout  = (const float*)d_in[6];
  const int*   imap  = (const int*)d_in[7];
  float* out = (float*)d_out;

  int NU = in_sizes[4] / 4096;     // 1122 unique 64x64 matrices

  // workspace layout (bytes)
  char* w8 = (char*)d_ws;
  unsigned short* wtb = (unsigned short*)w8;                 // NU*4096*2      = 9,191,424
  unsigned short* xnb = (unsigned short*)(w8 + 9191424);     // 197*8*64*2     =   201,728
  float* q    = (float*)(w8 + 9393152);                      // 16*197*32*4    =   403,456
  float* kk   = (float*)(w8 + 9796608);                      // 16*197*32*4    =   403,456
  float* attn = (float*)(w8 + 10200064);                     // 197*197*16*4   = 2,483,776
  float* part = (float*)(w8 + 12683840);                     // 16*197*8*64*4  = 6,455,296
                                                             // total ~19.2 MB

  k0_wt   <<<NU,          256, 0, stream>>>(up, wtb);
  k1_ln_qk<<<BATCH * NTOK, 64, 0, stream>>>(x, gamma, beta, wqk, xnb, q, kk);
  k2_attn <<<16 * NTOK,   256, 0, stream>>>(q, kk, attn);
  k3_main <<<NTOK * SPL,  256, 0, stream>>>(xnb, attn, wtb, imap, part);
  k4_out  <<<NTOK,        512, 0, stream>>>(part, wout, bout, out);
}